// Round 5
// baseline (468.675 us; speedup 1.0000x reference)
//
#include <hip/hip_runtime.h>
#include <hip/hip_bf16.h>
#include <math.h>

#define B_ 4
#define T_ 4096
#define H_ 16
#define D_ 64
#define C_ 1024
#define BT_ (B_*T_)

using short8  = __attribute__((ext_vector_type(8))) short;
using floatx4 = __attribute__((ext_vector_type(4))) float;

__device__ __forceinline__ float feature_map(float x) {
    return x > 0.0f ? x + 1.0f : __expf(x);   // elu(x)+1
}
__device__ __forceinline__ unsigned short f2bf(float x) {
    union { __hip_bfloat16 b; unsigned short u; } c;
    c.b = __float2bfloat16(x);                 // RNE
    return c.u;
}
__device__ __forceinline__ float bf2f(unsigned short u) {
    union { unsigned int u; float f; } c;
    c.u = (unsigned)u << 16;                   // exact
    return c.f;
}
__device__ __forceinline__ void async16(const void* g, void* l) {
    __builtin_amdgcn_global_load_lds(
        (const __attribute__((address_space(1))) void*)g,
        (__attribute__((address_space(3))) void*)l, 16, 0, 0);
}

// ---------------------------------------------------------------------------
// K0a: x fp32 -> bf16
// ---------------------------------------------------------------------------
__global__ __launch_bounds__(256)
void convert_x_kernel(const float4* __restrict__ x, ushort* __restrict__ xb)
{
    const size_t i = (size_t)blockIdx.x * 256 + threadIdx.x;
    const float4 v = x[i];
    *reinterpret_cast<ushort4*>(&xb[i * 4]) =
        make_ushort4(f2bf(v.x), f2bf(v.y), f2bf(v.z), f2bf(v.w));
}

// ---------------------------------------------------------------------------
// K0b: W[K][N] fp32 -> WT[N][K] bf16
// ---------------------------------------------------------------------------
__global__ __launch_bounds__(256)
void transpose_bf16_kernel(const float* __restrict__ W, ushort* __restrict__ WT,
                           int K, int N)
{
    __shared__ float t[32][33];
    const int n0 = blockIdx.x * 32, k0 = blockIdx.y * 32;
    const int r = threadIdx.x >> 5, c = threadIdx.x & 31;
    #pragma unroll
    for (int i = 0; i < 4; i++)
        t[r + 8 * i][c] = W[(size_t)(k0 + r + 8 * i) * N + n0 + c];
    __syncthreads();
    #pragma unroll
    for (int i = 0; i < 4; i++)
        WT[(size_t)(n0 + r + 8 * i) * K + k0 + c] = f2bf(t[c][r + 8 * i]);
}

// ---------------------------------------------------------------------------
// K1: per-head merged qkv GEMM [128x1024]x[1024x192(k|v|q)] bf16-MFMA.
// Epilogue: kT/vT transpose-store -> k^T v via MFMA -> atomicAdd kv;
//           q_m feature-mapped -> qws (bf16, [B,H,T,D]) via LDS staging.
// 4 waves as 2(M)x2(N=96); wave tile 64x96 = 4x6 MFMA tiles.
// ---------------------------------------------------------------------------
__global__ __launch_bounds__(256)
void qkv_kv_kernel(const ushort* __restrict__ xb, const ushort* __restrict__ WqkvT,
                   const float* __restrict__ bqkv, float* __restrict__ kv,
                   ushort* __restrict__ qws)
{
    __shared__ __align__(16) unsigned char smem[34816];
    ushort* As = (ushort*)smem;                  // [128][32] bf16 (main loop)
    ushort* Bs = (ushort*)(smem + 8192);         // [192][32] bf16 (12 KB)
    ushort* kT = (ushort*)smem;                  // [64][136] bf16 (epilogue)
    ushort* vT = kT + 64 * 136;                  // [64][136]
    ushort* qS = (ushort*)smem;                  // [128][72]  (after kv-MFMA)

    const int tid = threadIdx.x;
    const int w = tid >> 6, l = tid & 63;
    const int wm = w >> 1, wn = w & 1;
    const int lr = l & 15, quad = l >> 4;
    const int lk8 = quad * 8;
    const int h = blockIdx.x;
    const int mBase = blockIdx.y * 128;
    const int bb = mBase >> 12;
    const int tloc = mBase & (T_ - 1);

    // ---- staging coords ----
    const int srowA = w * 32 + (l >> 2);
    const int scolA = (l & 3) * 8;
    const ushort* gA = xb + (size_t)(mBase + srowA) * C_ + scolA;
    void* ldsA = (void*)(smem + w * 2048);

    // B local rows: [0,64)=k, [64,128)=v, [128,192)=q of head h
    const ushort* gB[3];
    void* ldsB[3];
    #pragma unroll
    for (int i = 0; i < 3; i++) {
        const int r = w * 48 + i * 16 + (l >> 2);
        const int grow = (r < 64)  ? (C_ + h * 64 + r)
                       : (r < 128) ? (2 * C_ + h * 64 + (r - 64))
                                   : (h * 64 + (r - 128));
        gB[i] = WqkvT + (size_t)grow * C_ + (l & 3) * 8;
        ldsB[i] = (void*)(smem + 8192 + w * 3072 + i * 1024);
    }

    floatx4 acc[4][6];
    #pragma unroll
    for (int i = 0; i < 4; i++)
        #pragma unroll
        for (int j = 0; j < 6; j++) acc[i][j] = (floatx4)0.0f;

    for (int k0 = 0; k0 < C_; k0 += 32) {
        __syncthreads();
        async16(gA + k0, ldsA);
        async16(gA + 16 * C_ + k0, (void*)((char*)ldsA + 1024));
        #pragma unroll
        for (int i = 0; i < 3; i++) async16(gB[i] + k0, ldsB[i]);
        __syncthreads();

        short8 af[4], bfr[6];
        #pragma unroll
        for (int mt = 0; mt < 4; mt++)
            af[mt] = *(const short8*)&As[(wm * 64 + mt * 16 + lr) * 32 + lk8];
        #pragma unroll
        for (int nt = 0; nt < 6; nt++)
            bfr[nt] = *(const short8*)&Bs[(wn * 96 + nt * 16 + lr) * 32 + lk8];
        #pragma unroll
        for (int mt = 0; mt < 4; mt++)
            #pragma unroll
            for (int nt = 0; nt < 6; nt++)
                acc[mt][nt] = __builtin_amdgcn_mfma_f32_16x16x32_bf16(
                    af[mt], bfr[nt], acc[mt][nt], 0, 0, 0);
    }

    const float inv_scale = 0.35355339059327373f;  // 1/64^0.25

    // ---- epilogue A: k_m, v -> transposed bf16 LDS ----
    __syncthreads();
    #pragma unroll
    for (int nt = 0; nt < 6; nt++) {
        const int ct = wn * 6 + nt;                // 0..11; 0-3=k, 4-7=v, 8-11=q
        if (ct < 8) {
            const bool isK = ct < 4;
            const int dcol = (ct - (isK ? 0 : 4)) * 16 + lr;   // 0..63
            const float bv = bqkv[(isK ? C_ : 2 * C_) + h * 64 + dcol];
            ushort* dst = isK ? kT : vT;
            #pragma unroll
            for (int mt = 0; mt < 4; mt++) {
                float v0 = acc[mt][nt][0] + bv, v1 = acc[mt][nt][1] + bv;
                float v2 = acc[mt][nt][2] + bv, v3 = acc[mt][nt][3] + bv;
                if (isK) {
                    v0 = feature_map(v0 * inv_scale); v1 = feature_map(v1 * inv_scale);
                    v2 = feature_map(v2 * inv_scale); v3 = feature_map(v3 * inv_scale);
                }
                *(ushort4*)&dst[dcol * 136 + wm * 64 + mt * 16 + quad * 4] =
                    make_ushort4(f2bf(v0), f2bf(v1), f2bf(v2), f2bf(v3));
            }
        }
    }
    __syncthreads();

    // ---- epilogue B: kv[d][m] += sum_t kT[d][t]*vT[m][t] (K=128) ----
    floatx4 acc2[2][2];
    #pragma unroll
    for (int i = 0; i < 2; i++)
        #pragma unroll
        for (int j = 0; j < 2; j++) acc2[i][j] = (floatx4)0.0f;

    #pragma unroll
    for (int kst = 0; kst < 4; kst++) {
        short8 afr[2], bfr[2];
        #pragma unroll
        for (int i = 0; i < 2; i++)
            afr[i] = *(const short8*)&kT[(wm * 32 + i * 16 + lr) * 136 + kst * 32 + lk8];
        #pragma unroll
        for (int j = 0; j < 2; j++)
            bfr[j] = *(const short8*)&vT[(wn * 32 + j * 16 + lr) * 136 + kst * 32 + lk8];
        #pragma unroll
        for (int i = 0; i < 2; i++)
            #pragma unroll
            for (int j = 0; j < 2; j++)
                acc2[i][j] = __builtin_amdgcn_mfma_f32_16x16x32_bf16(
                    afr[i], bfr[j], acc2[i][j], 0, 0, 0);
    }

    float* kvb = kv + (size_t)(bb * H_ + h) * (D_ * D_);
    #pragma unroll
    for (int i = 0; i < 2; i++)
        #pragma unroll
        for (int j = 0; j < 2; j++)
            #pragma unroll
            for (int r = 0; r < 4; r++)
                atomicAdd(&kvb[(wm * 32 + i * 16 + quad * 4 + r) * 64 + wn * 32 + j * 16 + lr],
                          acc2[i][j][r]);

    // ---- epilogue C: q_m -> qS (LDS) -> coalesced store to qws ----
    __syncthreads();                               // kT/vT reads drained
    if (wn == 1) {
        #pragma unroll
        for (int nt = 2; nt < 6; nt++) {
            const int qc = (nt - 2) * 16 + lr;     // 0..63
            const float bv = bqkv[h * 64 + qc];
            #pragma unroll
            for (int mt = 0; mt < 4; mt++)
                #pragma unroll
                for (int i = 0; i < 4; i++)
                    qS[(wm * 64 + mt * 16 + quad * 4 + i) * 72 + qc] =
                        f2bf(feature_map((acc[mt][nt][i] + bv) * inv_scale));
        }
    }
    __syncthreads();

    ushort* qdst = qws + ((size_t)(bb * H_ + h) * T_ + tloc) * 64;
    #pragma unroll
    for (int it = 0; it < 8; it++) {
        const int flat = it * 256 + tid;           // 0..2047
        const int row = flat >> 4, c4 = flat & 15;
        *(ushort4*)&qdst[(size_t)row * 64 + c4 * 4] =
            *(const ushort4*)&qS[row * 72 + c4 * 4];
    }
}

// ---------------------------------------------------------------------------
// K2: PV apply. attn[t, h*64+m] = (sum_d q_m[t][d]*kv[d][m]) / (z[t]+1e-6)
// block = (bh, 128-row tile); waves 2(t)x2(m); K=64 via 2 MFMA k-steps.
// ---------------------------------------------------------------------------
__global__ __launch_bounds__(256)
void pv_kernel(const ushort* __restrict__ qws, const float* __restrict__ kv,
               ushort* __restrict__ attn)
{
    __shared__ __align__(16) unsigned char smem[26112];
    ushort* qS  = (ushort*)smem;                  // [128][64] (16384 B)
    ushort* kvT = (ushort*)(smem + 16384);        // [64][72]  (9216 B)
    float*  zS  = (float*)(smem + 25600);         // [128]
    ushort* oS  = (ushort*)smem;                  // [128][72] (reuse after MFMA)

    const int tid = threadIdx.x;
    const int w = tid >> 6, l = tid & 63;
    const int wm = w >> 1, wn = w & 1;
    const int lr = l & 15, quad = l >> 4;
    const int lk8 = quad * 8;
    const int bh = blockIdx.x;
    const int b = bh >> 4, h = bh & 15;
    const int t0 = blockIdx.y * 128;

    // stage q tile (128x64 bf16) via async16
    {
        const int row8 = l >> 3, c8 = (l & 7) * 8;
        const ushort* gq = qws + ((size_t)bh * T_ + t0) * 64;
        #pragma unroll
        for (int i = 0; i < 4; i++) {
            const int rbase = (w * 4 + i) * 8;
            async16(gq + (size_t)(rbase + row8) * 64 + c8,
                    (void*)(smem + (w * 4 + i) * 1024));
        }
    }
    // kv fp32 -> kvT bf16 transposed [m][d]
    {
        const float* kvg = kv + (size_t)bh * (D_ * D_);
        #pragma unroll
        for (int e = 0; e < 16; e++) {
            const int flat = e * 256 + tid;
            const int d = flat >> 6, m = flat & 63;
            kvT[m * 72 + d] = f2bf(kvg[flat]);
        }
    }
    __syncthreads();

    // z row-sums (threads 0..127)
    if (tid < 128) {
        float s = 0.0f;
        #pragma unroll
        for (int c8 = 0; c8 < 8; c8++) {
            const short8 v = *(const short8*)&qS[tid * 64 + c8 * 8];
            #pragma unroll
            for (int j = 0; j < 8; j++) s += bf2f((unsigned short)v[j]);
        }
        zS[tid] = s;
    }

    floatx4 acc[4][2];
    #pragma unroll
    for (int i = 0; i < 4; i++)
        #pragma unroll
        for (int j = 0; j < 2; j++) acc[i][j] = (floatx4)0.0f;

    #pragma unroll
    for (int kst = 0; kst < 2; kst++) {
        short8 af[4], bf[2];
        #pragma unroll
        for (int mt = 0; mt < 4; mt++)
            af[mt] = *(const short8*)&qS[(wm * 64 + mt * 16 + lr) * 64 + kst * 32 + lk8];
        #pragma unroll
        for (int nt = 0; nt < 2; nt++)
            bf[nt] = *(const short8*)&kvT[(wn * 32 + nt * 16 + lr) * 72 + kst * 32 + lk8];
        #pragma unroll
        for (int mt = 0; mt < 4; mt++)
            #pragma unroll
            for (int nt = 0; nt < 2; nt++)
                acc[mt][nt] = __builtin_amdgcn_mfma_f32_16x16x32_bf16(
                    af[mt], bf[nt], acc[mt][nt], 0, 0, 0);
    }
    __syncthreads();                               // zS visible; qS/kvT reads done

    #pragma unroll
    for (int mt = 0; mt < 4; mt++)
        #pragma unroll
        for (int i = 0; i < 4; i++) {
            const int t = wm * 64 + mt * 16 + quad * 4 + i;
            const float inv = 1.0f / (zS[t] + 1e-6f);
            #pragma unroll
            for (int nt = 0; nt < 2; nt++)
                oS[t * 72 + wn * 32 + nt * 16 + lr] = f2bf(acc[mt][nt][i] * inv);
        }
    __syncthreads();

    #pragma unroll
    for (int it = 0; it < 8; it++) {
        const int flat = it * 256 + tid;           // 0..2047
        const int row = flat >> 4, c4 = flat & 15;
        *(ushort4*)&attn[(size_t)(b * T_ + t0 + row) * C_ + h * 64 + c4 * 4] =
            *(const ushort4*)&oS[row * 72 + c4 * 4];
    }
}

// ---------------------------------------------------------------------------
// K3: out-proj [16384x1024]x[1024x1024] bf16-MFMA, +bout, fp32 out
// ---------------------------------------------------------------------------
__global__ __launch_bounds__(256)
void outproj_mfma_kernel(const ushort* __restrict__ attn, const ushort* __restrict__ WoutT,
                         const float* __restrict__ bout, float* __restrict__ out)
{
    __shared__ __align__(16) unsigned char smem[16384];
    ushort* As = (ushort*)smem;
    ushort* Bs = (ushort*)(smem + 8192);

    const int tid = threadIdx.x;
    const int w = tid >> 6, l = tid & 63;
    const int wm = w >> 1, wn = w & 1;
    const int lr = l & 15, lk8 = (l >> 4) * 8;
    const int mBase = blockIdx.y * 128;
    const int nBase = blockIdx.x * 128;

    const int srow = w * 32 + (l >> 2);
    const int scol = (l & 3) * 8;
    const ushort* gA = attn + (size_t)(mBase + srow) * C_ + scol;
    const ushort* gB = WoutT + (size_t)(nBase + srow) * C_ + scol;
    void* ldsA = (void*)(smem + w * 2048);
    void* ldsB = (void*)(smem + 8192 + w * 2048);

    floatx4 acc[4][4];
    #pragma unroll
    for (int i = 0; i < 4; i++)
        #pragma unroll
        for (int j = 0; j < 4; j++) acc[i][j] = (floatx4)0.0f;

    for (int k0 = 0; k0 < C_; k0 += 32) {
        __syncthreads();
        async16(gA + k0, ldsA);
        async16(gA + 16 * C_ + k0, (void*)((char*)ldsA + 1024));
        async16(gB + k0, ldsB);
        async16(gB + 16 * C_ + k0, (void*)((char*)ldsB + 1024));
        __syncthreads();

        short8 af[4], bfr[4];
        #pragma unroll
        for (int mt = 0; mt < 4; mt++)
            af[mt] = *(const short8*)&As[(wm * 64 + mt * 16 + lr) * 32 + lk8];
        #pragma unroll
        for (int nt = 0; nt < 4; nt++)
            bfr[nt] = *(const short8*)&Bs[(wn * 64 + nt * 16 + lr) * 32 + lk8];
        #pragma unroll
        for (int mt = 0; mt < 4; mt++)
            #pragma unroll
            for (int nt = 0; nt < 4; nt++)
                acc[mt][nt] = __builtin_amdgcn_mfma_f32_16x16x32_bf16(
                    af[mt], bfr[nt], acc[mt][nt], 0, 0, 0);
    }

    #pragma unroll
    for (int mt = 0; mt < 4; mt++)
        #pragma unroll
        for (int nt = 0; nt < 4; nt++) {
            const int cc = nBase + wn * 64 + nt * 16 + lr;
            const float bv = bout[cc];
            #pragma unroll
            for (int i = 0; i < 4; i++) {
                const int rr = mBase + wm * 64 + mt * 16 + (l >> 4) * 4 + i;
                out[(size_t)rr * C_ + cc] = acc[mt][nt][i] + bv;
            }
        }
}

// ---------------------------------------------------------------------------
extern "C" void kernel_launch(void* const* d_in, const int* in_sizes, int n_in,
                              void* d_out, int out_size, void* d_ws, size_t ws_size,
                              hipStream_t stream)
{
    const float* x    = (const float*)d_in[0];
    const float* Wqkv = (const float*)d_in[1];
    const float* bqkv = (const float*)d_in[2];
    const float* Wout = (const float*)d_in[3];
    const float* bout = (const float*)d_in[4];
    float* out = (float*)d_out;

    char* ws = (char*)d_ws;
    ushort* xb     = (ushort*)ws;                       // 33,554,432 B (reused as attn)
    ushort* WqkvT  = (ushort*)(ws + 33554432);          //  6,291,456 B
    ushort* WoutT  = (ushort*)(ws + 39845888);          //  2,097,152 B
    ushort* qws    = (ushort*)(ws + 41943040);          // 33,554,432 B
    float*  kv     = (float*) (ws + 75497472);          //  1,048,576 B  (~73 MB total)
    ushort* attn   = xb;                                // xb dead after qkv_kv_kernel

    hipMemsetAsync(kv, 0, (size_t)B_ * H_ * D_ * D_ * sizeof(float), stream);

    convert_x_kernel<<<(BT_ * C_ / 4) / 256, 256, 0, stream>>>((const float4*)x, xb);
    transpose_bf16_kernel<<<dim3(3 * C_ / 32, C_ / 32), 256, 0, stream>>>(Wqkv, WqkvT, C_, 3 * C_);
    transpose_bf16_kernel<<<dim3(C_ / 32, C_ / 32), 256, 0, stream>>>(Wout, WoutT, C_, C_);

    qkv_kv_kernel<<<dim3(H_, BT_ / 128), 256, 0, stream>>>(xb, WqkvT, bqkv, kv, qws);
    pv_kernel<<<dim3(B_ * H_, T_ / 128), 256, 0, stream>>>(qws, kv, attn);
    outproj_mfma_kernel<<<dim3(C_ / 128, BT_ / 128), 256, 0, stream>>>(attn, WoutT, bout, out);
}

// Round 6
// 367.489 us; speedup vs baseline: 1.2753x; 1.2753x over previous
//
#include <hip/hip_runtime.h>
#include <hip/hip_bf16.h>
#include <math.h>

#define B_ 4
#define T_ 4096
#define H_ 16
#define D_ 64
#define C_ 1024
#define BT_ (B_*T_)

using short8  = __attribute__((ext_vector_type(8))) short;
using floatx4 = __attribute__((ext_vector_type(4))) float;

__device__ __forceinline__ float feature_map(float x) {
    return x > 0.0f ? x + 1.0f : __expf(x);   // elu(x)+1
}
__device__ __forceinline__ unsigned short f2bf(float x) {
    union { __hip_bfloat16 b; unsigned short u; } c;
    c.b = __float2bfloat16(x);                 // RNE
    return c.u;
}
__device__ __forceinline__ float bf2f(unsigned short u) {
    union { unsigned int u; float f; } c;
    c.u = (unsigned)u << 16;                   // exact
    return c.f;
}
__device__ __forceinline__ void async16(const void* g, void* l) {
    __builtin_amdgcn_global_load_lds(
        (const __attribute__((address_space(1))) void*)g,
        (__attribute__((address_space(3))) void*)l, 16, 0, 0);
}

// ---------------------------------------------------------------------------
// K0a: x fp32 -> bf16
// ---------------------------------------------------------------------------
__global__ __launch_bounds__(256)
void convert_x_kernel(const float4* __restrict__ x, ushort* __restrict__ xb)
{
    const size_t i = (size_t)blockIdx.x * 256 + threadIdx.x;
    const float4 v = x[i];
    *reinterpret_cast<ushort4*>(&xb[i * 4]) =
        make_ushort4(f2bf(v.x), f2bf(v.y), f2bf(v.z), f2bf(v.w));
}

// ---------------------------------------------------------------------------
// K0b: W[K][N] fp32 -> WT[N][K] bf16
// ---------------------------------------------------------------------------
__global__ __launch_bounds__(256)
void transpose_bf16_kernel(const float* __restrict__ W, ushort* __restrict__ WT,
                           int K, int N)
{
    __shared__ float t[32][33];
    const int n0 = blockIdx.x * 32, k0 = blockIdx.y * 32;
    const int r = threadIdx.x >> 5, c = threadIdx.x & 31;
    #pragma unroll
    for (int i = 0; i < 4; i++)
        t[r + 8 * i][c] = W[(size_t)(k0 + r + 8 * i) * N + n0 + c];
    __syncthreads();
    #pragma unroll
    for (int i = 0; i < 4; i++)
        WT[(size_t)(n0 + r + 8 * i) * K + k0 + c] = f2bf(t[c][r + 8 * i]);
}

// ---------------------------------------------------------------------------
// K1: per-head [128x1024]x[1024x128(k|v)] bf16-MFMA GEMM, epilogue:
//     k_m,v -> LDS transposed bf16 (stride 132: 4-way banks, was 8-way@136)
//     -> k^T v via MFMA -> atomicAdd.
// ---------------------------------------------------------------------------
__global__ __launch_bounds__(256)
void kv_mfma_kernel(const ushort* __restrict__ xb, const ushort* __restrict__ WqkvT,
                    const float* __restrict__ bqkv, float* __restrict__ kv)
{
    __shared__ __align__(16) unsigned char smem[33792];
    ushort* As = (ushort*)smem;                  // [128][32] bf16 (main loop)
    ushort* Bs = (ushort*)(smem + 8192);         // [128][32] bf16
    ushort* kT = (ushort*)smem;                  // [64][132] bf16 (epilogue)
    ushort* vT = kT + 64 * 132;                  // [64][132]

    const int tid = threadIdx.x;
    const int w = tid >> 6, l = tid & 63;
    const int wm = w >> 1, wn = w & 1;
    const int lr = l & 15, quad = l >> 4;
    const int lk8 = quad * 8;
    const int h = blockIdx.x;
    const int mBase = blockIdx.y * 128;
    const int bb = mBase >> 12;

    const int srow = w * 32 + (l >> 2);
    const int scol = (l & 3) * 8;
    const ushort* gA = xb + (size_t)(mBase + srow) * C_ + scol;
    const int br0 = (srow < 64)      ? (C_ + h * 64 + srow)      : (2 * C_ + h * 64 + srow - 64);
    const int br1 = (srow + 16 < 64) ? (C_ + h * 64 + srow + 16) : (2 * C_ + h * 64 + srow - 48);
    const ushort* gB0 = WqkvT + (size_t)br0 * C_ + scol;
    const ushort* gB1 = WqkvT + (size_t)br1 * C_ + scol;
    void* ldsA = (void*)(smem + w * 2048);
    void* ldsB = (void*)(smem + 8192 + w * 2048);

    floatx4 acc[4][4];
    #pragma unroll
    for (int i = 0; i < 4; i++)
        #pragma unroll
        for (int j = 0; j < 4; j++) acc[i][j] = (floatx4)0.0f;

    for (int k0 = 0; k0 < C_; k0 += 32) {
        __syncthreads();
        async16(gA + k0, ldsA);
        async16(gA + 16 * C_ + k0, (void*)((char*)ldsA + 1024));
        async16(gB0 + k0, ldsB);
        async16(gB1 + k0, (void*)((char*)ldsB + 1024));
        __syncthreads();

        short8 af[4], bf[4];
        #pragma unroll
        for (int mt = 0; mt < 4; mt++)
            af[mt] = *(const short8*)&As[(wm * 64 + mt * 16 + lr) * 32 + lk8];
        #pragma unroll
        for (int nt = 0; nt < 4; nt++)
            bf[nt] = *(const short8*)&Bs[(wn * 64 + nt * 16 + lr) * 32 + lk8];
        #pragma unroll
        for (int mt = 0; mt < 4; mt++)
            #pragma unroll
            for (int nt = 0; nt < 4; nt++)
                acc[mt][nt] = __builtin_amdgcn_mfma_f32_16x16x32_bf16(
                    af[mt], bf[nt], acc[mt][nt], 0, 0, 0);
    }

    // ---- epilogue: transpose-store k_m (bf16) and v (bf16), then MFMA k^T v
    const float inv_scale = 0.35355339059327373f;  // 1/64^0.25
    const int bbias = (wn ? 2 * C_ : C_) + h * 64;

    __syncthreads();                               // As/Bs reads drained
    {
        ushort* dst = wn ? vT : kT;
        #pragma unroll
        for (int nt = 0; nt < 4; nt++) {
            const int cc = nt * 16 + lr;           // d (k) or m (v), 0..63
            const float bv = bqkv[bbias + cc];
            #pragma unroll
            for (int mt = 0; mt < 4; mt++) {
                float v0 = acc[mt][nt][0] + bv, v1 = acc[mt][nt][1] + bv;
                float v2 = acc[mt][nt][2] + bv, v3 = acc[mt][nt][3] + bv;
                if (wn == 0) {
                    v0 = feature_map(v0 * inv_scale); v1 = feature_map(v1 * inv_scale);
                    v2 = feature_map(v2 * inv_scale); v3 = feature_map(v3 * inv_scale);
                }
                *(ushort4*)&dst[cc * 132 + wm * 64 + mt * 16 + quad * 4] =
                    make_ushort4(f2bf(v0), f2bf(v1), f2bf(v2), f2bf(v3));
            }
        }
    }
    __syncthreads();

    // kv[d][m] += sum_t kT[d][t] * vT[m][t] ; wave quadrant 32x32, K=128
    floatx4 acc2[2][2];
    #pragma unroll
    for (int i = 0; i < 2; i++)
        #pragma unroll
        for (int j = 0; j < 2; j++) acc2[i][j] = (floatx4)0.0f;

    #pragma unroll
    for (int kst = 0; kst < 4; kst++) {
        short8 afr[2], bfr[2];
        #pragma unroll
        for (int i = 0; i < 2; i++)
            afr[i] = *(const short8*)&kT[(wm * 32 + i * 16 + lr) * 132 + kst * 32 + lk8];
        #pragma unroll
        for (int j = 0; j < 2; j++)
            bfr[j] = *(const short8*)&vT[(wn * 32 + j * 16 + lr) * 132 + kst * 32 + lk8];
        #pragma unroll
        for (int i = 0; i < 2; i++)
            #pragma unroll
            for (int j = 0; j < 2; j++)
                acc2[i][j] = __builtin_amdgcn_mfma_f32_16x16x32_bf16(
                    afr[i], bfr[j], acc2[i][j], 0, 0, 0);
    }

    float* kvb = kv + (size_t)(bb * H_ + h) * (D_ * D_);
    #pragma unroll
    for (int i = 0; i < 2; i++)
        #pragma unroll
        for (int j = 0; j < 2; j++)
            #pragma unroll
            for (int r = 0; r < 4; r++) {
                const int d = wm * 32 + i * 16 + quad * 4 + r;
                const int m = wn * 32 + j * 16 + lr;
                atomicAdd(&kvb[d * 64 + m], acc2[i][j][r]);
            }
}

// ---------------------------------------------------------------------------
// K2: head-pair q GEMM [128x1024]x[1024x128] bf16-MFMA, epilogue:
//     qS bf16 [t][d] (stride 132) -> z row-sums -> PV via MFMA (kvT stride 68)
//     -> divide -> staged store.
// ---------------------------------------------------------------------------
__global__ __launch_bounds__(256)
void qattn_mfma_kernel(const ushort* __restrict__ xb, const ushort* __restrict__ WqkvT,
                       const float* __restrict__ bqkv, const float* __restrict__ kv,
                       ushort* __restrict__ attn)
{
    __shared__ __align__(16) unsigned char smem[52224];
    ushort* As  = (ushort*)smem;                  // [128][32] (main loop)
    ushort* Bs  = (ushort*)(smem + 8192);         // [128][32]
    ushort* qS  = (ushort*)smem;                  // [128][132] bf16 (33792 B; reused as oS)
    ushort* kvT = (ushort*)(smem + 33792);        // [2][64][68] bf16 (17408 B)
    float*  zS  = (float*)(smem + 51200);         // [2][128]

    const int tid = threadIdx.x;
    const int w = tid >> 6, l = tid & 63;
    const int wm = w >> 1, wn = w & 1;
    const int lr = l & 15, quad = l >> 4;
    const int lk8 = quad * 8;
    const int hp = blockIdx.x;                    // heads 2hp, 2hp+1
    const int mBase = blockIdx.y * 128;
    const int bb = mBase >> 12;

    // kv[b, 2hp+h][d][m] fp32 -> kvT[h][m][d] bf16
    {
        const float* kvg = kv + ((size_t)bb * H_ + hp * 2) * (D_ * D_);
        #pragma unroll
        for (int e = 0; e < 32; e++) {
            const int flat = e * 256 + tid;       // 0..8191
            const int hh = flat >> 12, d = (flat >> 6) & 63, m = flat & 63;
            kvT[hh * 4352 + m * 68 + d] = f2bf(kvg[flat]);
        }
    }

    const int srow = w * 32 + (l >> 2);
    const int scol = (l & 3) * 8;
    const ushort* gA = xb + (size_t)(mBase + srow) * C_ + scol;
    const ushort* gB = WqkvT + (size_t)(hp * 128 + srow) * C_ + scol;
    void* ldsA = (void*)(smem + w * 2048);
    void* ldsB = (void*)(smem + 8192 + w * 2048);

    floatx4 acc[4][4];
    #pragma unroll
    for (int i = 0; i < 4; i++)
        #pragma unroll
        for (int j = 0; j < 4; j++) acc[i][j] = (floatx4)0.0f;

    for (int k0 = 0; k0 < C_; k0 += 32) {
        __syncthreads();
        async16(gA + k0, ldsA);
        async16(gA + 16 * C_ + k0, (void*)((char*)ldsA + 1024));
        async16(gB + k0, ldsB);
        async16(gB + 16 * C_ + k0, (void*)((char*)ldsB + 1024));
        __syncthreads();

        short8 af[4], bfr[4];
        #pragma unroll
        for (int mt = 0; mt < 4; mt++)
            af[mt] = *(const short8*)&As[(wm * 64 + mt * 16 + lr) * 32 + lk8];
        #pragma unroll
        for (int nt = 0; nt < 4; nt++)
            bfr[nt] = *(const short8*)&Bs[(wn * 64 + nt * 16 + lr) * 32 + lk8];
        #pragma unroll
        for (int mt = 0; mt < 4; mt++)
            #pragma unroll
            for (int nt = 0; nt < 4; nt++)
                acc[mt][nt] = __builtin_amdgcn_mfma_f32_16x16x32_bf16(
                    af[mt], bfr[nt], acc[mt][nt], 0, 0, 0);
    }

    const float inv_scale = 0.35355339059327373f;

    __syncthreads();                               // As/Bs reads drained
    // q_m -> qS[t][cc] bf16 (cc = wn*64 + nt*16 + lr spans both heads)
    #pragma unroll
    for (int nt = 0; nt < 4; nt++) {
        const int cc = wn * 64 + nt * 16 + lr;
        const float bv = bqkv[hp * 128 + cc];
        #pragma unroll
        for (int mt = 0; mt < 4; mt++)
            #pragma unroll
            for (int i = 0; i < 4; i++) {
                const int t = wm * 64 + mt * 16 + quad * 4 + i;
                qS[t * 132 + cc] = f2bf(feature_map((acc[mt][nt][i] + bv) * inv_scale));
            }
    }
    __syncthreads();

    // z[h][t] = sum_d qS[t][h*64+d]   (one (t,h) per thread)
    {
        const int t = tid & 127, hh = tid >> 7;
        float s = 0.0f;
        #pragma unroll
        for (int c8 = 0; c8 < 8; c8++) {
            const short8 v = *(const short8*)&qS[t * 132 + hh * 64 + c8 * 8];
            #pragma unroll
            for (int j = 0; j < 8; j++) s += bf2f((unsigned short)v[j]);
        }
        zS[hh * 128 + t] = s;
    }

    // PV: out_h[t][m] = sum_d qS[t][h*64+d] * kvT[h][m][d]; wave: h=wn, t-half=wm
    floatx4 acc3[4][4];
    #pragma unroll
    for (int i = 0; i < 4; i++)
        #pragma unroll
        for (int j = 0; j < 4; j++) acc3[i][j] = (floatx4)0.0f;

    #pragma unroll
    for (int kst = 0; kst < 2; kst++) {
        short8 afr[4], bfr[4];
        #pragma unroll
        for (int mt = 0; mt < 4; mt++)
            afr[mt] = *(const short8*)&qS[(wm * 64 + mt * 16 + lr) * 132 + wn * 64 + kst * 32 + lk8];
        #pragma unroll
        for (int nt = 0; nt < 4; nt++)
            bfr[nt] = *(const short8*)&kvT[wn * 4352 + (nt * 16 + lr) * 68 + kst * 32 + lk8];
        #pragma unroll
        for (int mt = 0; mt < 4; mt++)
            #pragma unroll
            for (int nt = 0; nt < 4; nt++)
                acc3[mt][nt] = __builtin_amdgcn_mfma_f32_16x16x32_bf16(
                    afr[mt], bfr[nt], acc3[mt][nt], 0, 0, 0);
    }
    __syncthreads();                               // zS visible; qS reads drained

    // divide by z, stage bf16 result into qS region (oS[t][h*64+m])
    #pragma unroll
    for (int mt = 0; mt < 4; mt++)
        #pragma unroll
        for (int i = 0; i < 4; i++) {
            const int t = wm * 64 + mt * 16 + quad * 4 + i;
            const float inv = 1.0f / (zS[wn * 128 + t] + 1e-6f);
            #pragma unroll
            for (int nt = 0; nt < 4; nt++)
                qS[t * 132 + wn * 64 + nt * 16 + lr] = f2bf(acc3[mt][nt][i] * inv);
        }
    __syncthreads();

    // coalesced copy-out: 128 rows x 128 ushorts
    #pragma unroll
    for (int it = 0; it < 16; it++) {
        const int flat = it * 256 + tid;          // 0..4095
        const int row = flat >> 5, c = flat & 31;
        *(ushort4*)&attn[(size_t)(mBase + row) * C_ + hp * 128 + c * 4] =
            *(const ushort4*)&qS[row * 132 + c * 4];
    }
}

// ---------------------------------------------------------------------------
// K3: out-proj [16384x1024]x[1024x1024] bf16-MFMA, +bout, fp32 out
// ---------------------------------------------------------------------------
__global__ __launch_bounds__(256)
void outproj_mfma_kernel(const ushort* __restrict__ attn, const ushort* __restrict__ WoutT,
                         const float* __restrict__ bout, float* __restrict__ out)
{
    __shared__ __align__(16) unsigned char smem[16384];
    ushort* As = (ushort*)smem;
    ushort* Bs = (ushort*)(smem + 8192);

    const int tid = threadIdx.x;
    const int w = tid >> 6, l = tid & 63;
    const int wm = w >> 1, wn = w & 1;
    const int lr = l & 15, lk8 = (l >> 4) * 8;
    const int mBase = blockIdx.y * 128;
    const int nBase = blockIdx.x * 128;

    const int srow = w * 32 + (l >> 2);
    const int scol = (l & 3) * 8;
    const ushort* gA = attn + (size_t)(mBase + srow) * C_ + scol;
    const ushort* gB = WoutT + (size_t)(nBase + srow) * C_ + scol;
    void* ldsA = (void*)(smem + w * 2048);
    void* ldsB = (void*)(smem + 8192 + w * 2048);

    floatx4 acc[4][4];
    #pragma unroll
    for (int i = 0; i < 4; i++)
        #pragma unroll
        for (int j = 0; j < 4; j++) acc[i][j] = (floatx4)0.0f;

    for (int k0 = 0; k0 < C_; k0 += 32) {
        __syncthreads();
        async16(gA + k0, ldsA);
        async16(gA + 16 * C_ + k0, (void*)((char*)ldsA + 1024));
        async16(gB + k0, ldsB);
        async16(gB + 16 * C_ + k0, (void*)((char*)ldsB + 1024));
        __syncthreads();

        short8 af[4], bfr[4];
        #pragma unroll
        for (int mt = 0; mt < 4; mt++)
            af[mt] = *(const short8*)&As[(wm * 64 + mt * 16 + lr) * 32 + lk8];
        #pragma unroll
        for (int nt = 0; nt < 4; nt++)
            bfr[nt] = *(const short8*)&Bs[(wn * 64 + nt * 16 + lr) * 32 + lk8];
        #pragma unroll
        for (int mt = 0; mt < 4; mt++)
            #pragma unroll
            for (int nt = 0; nt < 4; nt++)
                acc[mt][nt] = __builtin_amdgcn_mfma_f32_16x16x32_bf16(
                    af[mt], bfr[nt], acc[mt][nt], 0, 0, 0);
    }

    #pragma unroll
    for (int mt = 0; mt < 4; mt++)
        #pragma unroll
        for (int nt = 0; nt < 4; nt++) {
            const int cc = nBase + wn * 64 + nt * 16 + lr;
            const float bv = bout[cc];
            #pragma unroll
            for (int i = 0; i < 4; i++) {
                const int rr = mBase + wm * 64 + mt * 16 + (l >> 4) * 4 + i;
                out[(size_t)rr * C_ + cc] = acc[mt][nt][i] + bv;
            }
        }
}

// ---------------------------------------------------------------------------
extern "C" void kernel_launch(void* const* d_in, const int* in_sizes, int n_in,
                              void* d_out, int out_size, void* d_ws, size_t ws_size,
                              hipStream_t stream)
{
    const float* x    = (const float*)d_in[0];
    const float* Wqkv = (const float*)d_in[1];
    const float* bqkv = (const float*)d_in[2];
    const float* Wout = (const float*)d_in[3];
    const float* bout = (const float*)d_in[4];
    float* out = (float*)d_out;

    char* ws = (char*)d_ws;
    ushort* xb     = (ushort*)ws;                       // 33,554,432 B
    ushort* WqkvT  = (ushort*)(ws + 33554432);          //  6,291,456 B
    ushort* WoutT  = (ushort*)(ws + 39845888);          //  2,097,152 B
    ushort* attn   = (ushort*)(ws + 41943040);          // 33,554,432 B
    float*  kv     = (float*) (ws + 75497472);          //  1,048,576 B

    hipMemsetAsync(kv, 0, (size_t)B_ * H_ * D_ * D_ * sizeof(float), stream);

    convert_x_kernel<<<(BT_ * C_ / 4) / 256, 256, 0, stream>>>((const float4*)x, xb);
    transpose_bf16_kernel<<<dim3(3 * C_ / 32, C_ / 32), 256, 0, stream>>>(Wqkv, WqkvT, C_, 3 * C_);
    transpose_bf16_kernel<<<dim3(C_ / 32, C_ / 32), 256, 0, stream>>>(Wout, WoutT, C_, C_);

    kv_mfma_kernel<<<dim3(H_, BT_ / 128), 256, 0, stream>>>(xb, WqkvT, bqkv, kv);
    qattn_mfma_kernel<<<dim3(H_ / 2, BT_ / 128), 256, 0, stream>>>(xb, WqkvT, bqkv, kv, attn);
    outproj_mfma_kernel<<<dim3(C_ / 128, BT_ / 128), 256, 0, stream>>>(attn, WoutT, bout, out);
}